// Round 6
// baseline (285.550 us; speedup 1.0000x reference)
//
#include <hip/hip_runtime.h>
#include <stdint.h>

#define BB 4
#define SEQ 2048
#define DMODEL 1024
#define NHEAD 16
#define HDIM 64
#define INTER 1024
// attn scale folded into q at GEMM1 epilogue, with log2(e) so softmax is exp2:
// 0.03125 * 1.4426950408889634
#define QSCALE 0.045084220027780106f

#if __has_builtin(__builtin_amdgcn_exp2f)
#define EXP2F(x) __builtin_amdgcn_exp2f(x)
#else
#define EXP2F(x) exp2f(x)
#endif

typedef unsigned short u16;
typedef __attribute__((ext_vector_type(4))) unsigned short u16x4;
typedef __attribute__((ext_vector_type(4))) short s16x4;
typedef __attribute__((ext_vector_type(8))) short s16x8;   // 8 bf16 (4 VGPRs) MFMA A/B frag
typedef __attribute__((ext_vector_type(4))) float f32x4;
typedef __attribute__((ext_vector_type(16))) float f32x16; // 32x32 MFMA C/D frag

__device__ __forceinline__ u16 f2bf(float f) {
  unsigned int u = __float_as_uint(f);
  u += 0x7FFFu + ((u >> 16) & 1u);   // RNE
  return (u16)(u >> 16);
}

// pack 2 fp32 -> 2 bf16 in one dword (lo = a, hi = b)
#if __has_builtin(__builtin_amdgcn_cvt_pk_bf16_f32)
typedef __attribute__((ext_vector_type(2))) __bf16 bf16x2_t;
__device__ __forceinline__ unsigned int pk2bf(float a, float b) {
  bf16x2_t r = __builtin_amdgcn_cvt_pk_bf16_f32(a, b);
  return *reinterpret_cast<unsigned int*>(&r);
}
#else
__device__ __forceinline__ unsigned int pk2bf(float a, float b) {
  return (unsigned int)f2bf(a) | ((unsigned int)f2bf(b) << 16);
}
#endif

// async global->LDS, 16B per lane; LDS dest is wave-uniform base + lane*16
__device__ __forceinline__ void async16(const u16* g, u16* l) {
  __builtin_amdgcn_global_load_lds((__attribute__((address_space(1))) void*)(void*)(g),
                                   (__attribute__((address_space(3))) void*)(l),
                                   16, 0, 0);
}

// ------------- fused prep: cast features + transpose-cast both weights -------------
__global__ __launch_bounds__(256) void prep(
    const float* __restrict__ f, const float* __restrict__ wqkv,
    const float* __restrict__ wout, u16* __restrict__ Xb,
    u16* __restrict__ WqkvT, u16* __restrict__ WoutT) {
  __shared__ float tile[32][33];
  const int bid = blockIdx.x, tid = threadIdx.x;
  if (bid < 8192) {                       // cast features (exactly 8M elements)
    int i = (bid * 256 + tid) * 4;
    f32x4 v = *reinterpret_cast<const f32x4*>(f + i);
    uint2 o;
    o.x = pk2bf(v[0], v[1]);
    o.y = pk2bf(v[2], v[3]);
    *reinterpret_cast<uint2*>(Xb + i) = o;
  } else {                                // transpose-cast a 32x32 tile
    const float* src; u16* dst; int rows, cols, bx, by;
    if (bid < 8192 + 3072) {
      int t = bid - 8192;
      src = wqkv; dst = WqkvT; rows = DMODEL; cols = 3 * INTER;
      bx = t % 96; by = t / 96;
    } else {
      int t = bid - 11264;
      src = wout; dst = WoutT; rows = INTER; cols = DMODEL;
      bx = t & 31; by = t >> 5;
    }
    int c0 = bx * 32, r0 = by * 32, tx = tid & 31, ty = tid >> 5;
    #pragma unroll
    for (int i = ty; i < 32; i += 8) tile[i][tx] = src[(size_t)(r0 + i) * cols + c0 + tx];
    __syncthreads();
    #pragma unroll
    for (int i = ty; i < 32; i += 8)
      dst[(size_t)(c0 + i) * rows + r0 + tx] = f2bf(tile[tx][i]);
  }
}

// ---------------- bf16 GEMM, B-transposed input (m97 structure) ----------------
// MODE 0: q -> Qb row-major (scaled); k -> Kr row-major (repacked to Kp by
//         repack_k afterwards); v -> Vp fragment-packed (4 regs contiguous ->
//         one b64 store). Region branch is wave-uniform.
// MODE 1: C -> fp32 Cf.
template <int MODE>
__global__ __launch_bounds__(256, 2) void gemm_bt(
    const u16* __restrict__ A, const u16* __restrict__ BT,
    float* __restrict__ Cf, u16* __restrict__ Qb, u16* __restrict__ Kr,
    u16* __restrict__ Vp, int K, int ldc) {
  __shared__ u16 As[128 * 32];
  __shared__ u16 Bs[128 * 32];
  const int tid = threadIdx.x;
  const int wave = tid >> 6, lane = tid & 63;
  const int row0 = blockIdx.y * 128, col0 = blockIdx.x * 128;
  const int wr = (wave >> 1) * 64, wc = (wave & 1) * 64;
  const int r = lane & 15, q8 = (lane >> 4) * 8;

  f32x4 acc[4][4] = {};

  const int sRow = lane >> 2, sK = (lane & 3) * 8;
  const u16* Ag0 = A + (size_t)(row0 + wave * 32 + sRow) * K + sK;
  const u16* Ag1 = Ag0 + (size_t)16 * K;
  const u16* Bg0 = BT + (size_t)(col0 + wave * 32 + sRow) * K + sK;
  const u16* Bg1 = Bg0 + (size_t)16 * K;
  u16* Al0 = &As[wave * 1024];
  u16* Al1 = Al0 + 512;
  u16* Bl0 = &Bs[wave * 1024];
  u16* Bl1 = Bl0 + 512;

  for (int k0 = 0; k0 < K; k0 += 32) {
    async16(Ag0 + k0, Al0);
    async16(Ag1 + k0, Al1);
    async16(Bg0 + k0, Bl0);
    async16(Bg1 + k0, Bl1);
    __syncthreads();
    s16x8 af[4], bf[4];
    #pragma unroll
    for (int t = 0; t < 4; t++) {
      af[t] = *reinterpret_cast<const s16x8*>(&As[(wr + t * 16 + r) * 32 + q8]);
      bf[t] = *reinterpret_cast<const s16x8*>(&Bs[(wc + t * 16 + r) * 32 + q8]);
    }
    #pragma unroll
    for (int i = 0; i < 4; i++)
      #pragma unroll
      for (int j = 0; j < 4; j++)
        acc[i][j] = __builtin_amdgcn_mfma_f32_16x16x32_bf16(af[i], bf[j], acc[i][j], 0, 0, 0);
    __syncthreads();
  }

  const int quad = lane >> 4;
  #pragma unroll
  for (int i = 0; i < 4; i++) {
    const int n = row0 + wr + i * 16 + quad * 4;   // global row for regs 0..3
    const int b = n >> 11, nn = n & (SEQ - 1);
    #pragma unroll
    for (int j = 0; j < 4; j++) {
      const int gc = col0 + wc + j * 16 + r;       // wave-uniform region
      if (MODE == 1) {
        #pragma unroll
        for (int reg = 0; reg < 4; reg++)
          Cf[(size_t)(n + reg) * ldc + gc] = acc[i][j][reg];
      } else if (gc < INTER) {                     // q: row-major, scaled
        size_t base = (size_t)n * INTER + gc;
        #pragma unroll
        for (int reg = 0; reg < 4; reg++)
          Qb[base + (size_t)reg * INTER] = f2bf(acc[i][j][reg] * QSCALE);
      } else if (gc < 2 * INTER) {                 // k: row-major -> Kr
        size_t base = (size_t)n * INTER + (gc - INTER);
        #pragma unroll
        for (int reg = 0; reg < 4; reg++)
          Kr[base + (size_t)reg * INTER] = f2bf(acc[i][j][reg]);
      } else {                                     // v -> Vp packed, b64 store
        int dim = gc - 2 * INTER, h = dim >> 6, d = dim & 63;
        int bh = b * NHEAD + h;
        size_t base = ((((size_t)(bh * 64 + (nn >> 5)) * 2 + ((nn >> 4) & 1)) * 2 +
                        (d >> 5)) * 64 +
                       ((((nn >> 3) & 1) << 5) | (d & 31))) * 8 + (nn & 7);
        uint2 pk;
        pk.x = pk2bf(acc[i][j][0], acc[i][j][1]);
        pk.y = pk2bf(acc[i][j][2], acc[i][j][3]);
        *reinterpret_cast<uint2*>(Vp + base) = pk;
      }
    }
  }
}

// ------- repack K: row-major Kr -> fragment-packed Kp (streaming, 16B/thread) -------
// Kp element (bh, jb, c, half, l31, e) = K[b][n=jb*32+l31][h*64 + c*16+half*8+e].
// Reads coalesced (consecutive tids -> consecutive 16B); writes 16B chunks.
__global__ __launch_bounds__(256) void repack_k(const u16* __restrict__ Kr,
                                               u16* __restrict__ Kp) {
  const int bh = blockIdx.x, jb = blockIdx.y;
  const int b = bh >> 4, h = bh & 15;
  const int tid = threadIdx.x;
  const int nn = jb * 32 + (tid >> 3);
  const int d8 = (tid & 7) * 8;
  s16x8 v = *reinterpret_cast<const s16x8*>(
      Kr + (size_t)(b * SEQ + nn) * INTER + h * HDIM + d8);
  size_t dst = (size_t)bh * 131072 + (size_t)jb * 2048 +
               (size_t)(d8 >> 4) * 512 + (size_t)((d8 >> 3) & 1) * 256 +
               (size_t)(nn & 31) * 8;
  *reinterpret_cast<s16x8*>(Kp + dst) = v;
}

// ---------------- flash-style attention, fragment-packed operands ----------------
// grid: (B*H, SEQ/128); block 256 = 4 waves; wave owns 32 q-rows; no barriers.
// S^T = K·Q^T via 32x32x16 MFMA. q pre-scaled by SCALE*log2e -> p = exp2(s).
// No max-shift (scores bounded ~|s|<4 by construction).
// K/V fragments are dense 1 KB loads from packed layouts (lane*16B).
// Unrolled x2 with alternating K-frag buffers; P round-trips per-wave LDS
// (stride 36 u16, conflict-free).
#define ATTN_STEP(JCUR, KC, KN)                                                   \
  {                                                                               \
    const int jnext = ((JCUR) + 1) & 63;                                          \
    _Pragma("unroll")                                                             \
    for (int c = 0; c < 4; c++)                                                   \
      KN[c] = *reinterpret_cast<const s16x8*>(kpb + jnext * 2048 + c * 512);      \
    s16x8 vf[4];                                                                  \
    _Pragma("unroll")                                                             \
    for (int c = 0; c < 4; c++)                                                   \
      vf[c] = *reinterpret_cast<const s16x8*>(vpb + (JCUR) * 2048 + c * 512);     \
    f32x16 st = {};                                                               \
    _Pragma("unroll")                                                             \
    for (int c = 0; c < 4; c++)                                                   \
      st = __builtin_amdgcn_mfma_f32_32x32x16_bf16(KC[c], qf[c], st, 0, 0, 0);    \
    _Pragma("unroll")                                                             \
    for (int q = 0; q < 4; q++) {                                                 \
      float p0 = EXP2F(st[q * 4 + 0]), p1 = EXP2F(st[q * 4 + 1]);                 \
      float p2 = EXP2F(st[q * 4 + 2]), p3 = EXP2F(st[q * 4 + 3]);                 \
      ls += (p0 + p1) + (p2 + p3);                                                \
      uint2 pk;                                                                   \
      pk.x = pk2bf(p0, p1);                                                       \
      pk.y = pk2bf(p2, p3);                                                       \
      *reinterpret_cast<uint2*>(&Pw[l31 * 36 + q * 8 + half * 4]) = pk;           \
    }                                                                             \
    _Pragma("unroll")                                                             \
    for (int kc = 0; kc < 2; kc++) {                                              \
      const u16* pp = &Pw[l31 * 36 + half * 8 + kc * 16];                         \
      s16x4 plo = *reinterpret_cast<const s16x4*>(pp);                            \
      s16x4 phi = *reinterpret_cast<const s16x4*>(pp + 4);                        \
      s16x8 pb = __builtin_shufflevector(plo, phi, 0, 1, 2, 3, 4, 5, 6, 7);       \
      ot0 = __builtin_amdgcn_mfma_f32_32x32x16_bf16(vf[kc * 2 + 0], pb, ot0, 0, 0, 0); \
      ot1 = __builtin_amdgcn_mfma_f32_32x32x16_bf16(vf[kc * 2 + 1], pb, ot1, 0, 0, 0); \
    }                                                                             \
  }

__global__ __launch_bounds__(256, 4) void attn_kernel(
    const u16* __restrict__ Qb, const u16* __restrict__ Kp,
    const u16* __restrict__ Vp, u16* __restrict__ AO) {
  __shared__ __align__(16) u16 Ps[4][32 * 36];
  const int tid = threadIdx.x;
  const int wave = tid >> 6, lane = tid & 63;
  const int l31 = lane & 31, half = lane >> 5;
  const int bh = blockIdx.x, b = bh >> 4, h = bh & 15;
  const int i0 = blockIdx.y * 128 + wave * 32;

  // Q fragments (B-operand): B[n=q-row][k=d], k-contiguous. Once per wave.
  const u16* qbase = Qb + (size_t)(b * SEQ + i0 + l31) * INTER + h * HDIM + half * 8;
  s16x8 qf[4];
  #pragma unroll
  for (int c = 0; c < 4; c++) qf[c] = *reinterpret_cast<const s16x8*>(qbase + c * 16);

  const u16* kpb = Kp + (size_t)bh * (64 * 4 * 512) + lane * 8;   // + jblk*2048 + c*512
  const u16* vpb = Vp + (size_t)bh * (64 * 4 * 512) + lane * 8;   // + jblk*2048 + (kc*2+dgrp)*512
  u16* Pw = &Ps[wave][0];

  f32x16 ot0 = {}, ot1 = {};
  float ls = 0.f;

  s16x8 kf0[4], kf1[4];
  #pragma unroll
  for (int c = 0; c < 4; c++)
    kf0[c] = *reinterpret_cast<const s16x8*>(kpb + c * 512);

  for (int jb = 0; jb < 64; jb += 2) {
    ATTN_STEP(jb, kf0, kf1)
    ATTN_STEP(jb + 1, kf1, kf0)
  }

  ls += __shfl_xor(ls, 32, 64);      // lanes L, L+32 hold complementary j-halves
  float rinv = 1.0f / ls;

  u16* orow = AO + (size_t)(b * SEQ + i0 + l31) * INTER + h * HDIM;
  #pragma unroll
  for (int dt = 0; dt < 2; dt++) {
    const f32x16& o = dt ? ot1 : ot0;
    #pragma unroll
    for (int q = 0; q < 4; q++) {
      uint2 pk;
      pk.x = pk2bf(o[q * 4 + 0] * rinv, o[q * 4 + 1] * rinv);
      pk.y = pk2bf(o[q * 4 + 2] * rinv, o[q * 4 + 3] * rinv);
      *reinterpret_cast<uint2*>(orow + dt * 32 + q * 8 + half * 4) = pk;
    }
  }
}

extern "C" void kernel_launch(void* const* d_in, const int* in_sizes, int n_in,
                              void* d_out, int out_size, void* d_ws, size_t ws_size,
                              hipStream_t stream) {
  const float* features = (const float*)d_in[0];
  const float* W_qkv    = (const float*)d_in[1];
  const float* W_out    = (const float*)d_in[2];
  float* out = (float*)d_out;
  char* w = (char*)d_ws;
  u16* Xb    = (u16*)(w);              // [8192][1024] bf16 features      16 MB
  u16* WqkvT = (u16*)(w + 16777216);   // [3072][1024] bf16 W_qkv^T        6 MB
  u16* WoutT = (u16*)(w + 23068672);   // [1024][1024] bf16 W_out^T        2 MB
  u16* Qb    = (u16*)(w + 25165824);   // [8192][1024] bf16 q (scaled)    16 MB
  u16* Kp    = (u16*)(w + 41943040);   // fragment-packed K               16 MB
  u16* Vp    = (u16*)(w + 58720256);   // fragment-packed V               16 MB
  u16* AO    = (u16*)(w + 75497472);   // attn out; aliased as Kr before attn
  u16* Kr    = AO;                     // row-major K (dead once Kp built)

  prep<<<dim3(12288), dim3(256), 0, stream>>>(features, W_qkv, W_out, Xb, WqkvT, WoutT);
  gemm_bt<0><<<dim3(24, 64), dim3(256), 0, stream>>>(Xb, WqkvT, nullptr, Qb, Kr, Vp,
                                                     DMODEL, 0);
  repack_k<<<dim3(64, 64), dim3(256), 0, stream>>>(Kr, Kp);
  attn_kernel<<<dim3(64, 16), dim3(256), 0, stream>>>(Qb, Kp, Vp, AO);
  gemm_bt<1><<<dim3(8, 64), dim3(256), 0, stream>>>(AO, WoutT, out, nullptr, nullptr,
                                                    nullptr, INTER, DMODEL);
}

// Round 7
// 282.333 us; speedup vs baseline: 1.0114x; 1.0114x over previous
//
#include <hip/hip_runtime.h>
#include <stdint.h>

#define BB 4
#define SEQ 2048
#define DMODEL 1024
#define NHEAD 16
#define HDIM 64
#define INTER 1024
// attn scale folded into q at GEMM1 epilogue, with log2(e) so softmax is exp2:
// 0.03125 * 1.4426950408889634
#define QSCALE 0.045084220027780106f

#if __has_builtin(__builtin_amdgcn_exp2f)
#define EXP2F(x) __builtin_amdgcn_exp2f(x)
#else
#define EXP2F(x) exp2f(x)
#endif

typedef unsigned short u16;
typedef __attribute__((ext_vector_type(4))) unsigned short u16x4;
typedef __attribute__((ext_vector_type(4))) short s16x4;
typedef __attribute__((ext_vector_type(8))) short s16x8;   // 8 bf16 (4 VGPRs) MFMA A/B frag
typedef __attribute__((ext_vector_type(4))) float f32x4;
typedef __attribute__((ext_vector_type(16))) float f32x16; // 32x32 MFMA C/D frag

__device__ __forceinline__ u16 f2bf(float f) {
  unsigned int u = __float_as_uint(f);
  u += 0x7FFFu + ((u >> 16) & 1u);   // RNE
  return (u16)(u >> 16);
}

// pack 2 fp32 -> 2 bf16 in one dword (lo = a, hi = b)
#if __has_builtin(__builtin_amdgcn_cvt_pk_bf16_f32)
typedef __attribute__((ext_vector_type(2))) __bf16 bf16x2_t;
__device__ __forceinline__ unsigned int pk2bf(float a, float b) {
  bf16x2_t r = __builtin_amdgcn_cvt_pk_bf16_f32(a, b);
  return *reinterpret_cast<unsigned int*>(&r);
}
#else
__device__ __forceinline__ unsigned int pk2bf(float a, float b) {
  return (unsigned int)f2bf(a) | ((unsigned int)f2bf(b) << 16);
}
#endif

// async global->LDS, 16B per lane; LDS dest is wave-uniform base + lane*16
__device__ __forceinline__ void async16(const u16* g, u16* l) {
  __builtin_amdgcn_global_load_lds((__attribute__((address_space(1))) void*)(void*)(g),
                                   (__attribute__((address_space(3))) void*)(l),
                                   16, 0, 0);
}

// ------------- fused prep: cast features + transpose-cast both weights -------------
__global__ __launch_bounds__(256) void prep(
    const float* __restrict__ f, const float* __restrict__ wqkv,
    const float* __restrict__ wout, u16* __restrict__ Xb,
    u16* __restrict__ WqkvT, u16* __restrict__ WoutT) {
  __shared__ float tile[32][33];
  const int bid = blockIdx.x, tid = threadIdx.x;
  if (bid < 8192) {                       // cast features (exactly 8M elements)
    int i = (bid * 256 + tid) * 4;
    f32x4 v = *reinterpret_cast<const f32x4*>(f + i);
    uint2 o;
    o.x = pk2bf(v[0], v[1]);
    o.y = pk2bf(v[2], v[3]);
    *reinterpret_cast<uint2*>(Xb + i) = o;
  } else {                                // transpose-cast a 32x32 tile
    const float* src; u16* dst; int rows, cols, bx, by;
    if (bid < 8192 + 3072) {
      int t = bid - 8192;
      src = wqkv; dst = WqkvT; rows = DMODEL; cols = 3 * INTER;
      bx = t % 96; by = t / 96;
    } else {
      int t = bid - 11264;
      src = wout; dst = WoutT; rows = INTER; cols = DMODEL;
      bx = t & 31; by = t >> 5;
    }
    int c0 = bx * 32, r0 = by * 32, tx = tid & 31, ty = tid >> 5;
    #pragma unroll
    for (int i = ty; i < 32; i += 8) tile[i][tx] = src[(size_t)(r0 + i) * cols + c0 + tx];
    __syncthreads();
    #pragma unroll
    for (int i = ty; i < 32; i += 8)
      dst[(size_t)(c0 + i) * rows + r0 + tx] = f2bf(tile[tx][i]);
  }
}

// ---------------- bf16 GEMM, B-transposed input (m97 structure) ----------------
// MODE 0: q -> Qb row-major (scaled); k -> Kp fragment-packed (base + reg*8
//         stores); v -> Vp fragment-packed (4 regs contiguous -> one b64
//         store). Index math hoisted per-(i,j); region branch wave-uniform.
// MODE 1: C -> fp32 Cf.
template <int MODE>
__global__ __launch_bounds__(256, 2) void gemm_bt(
    const u16* __restrict__ A, const u16* __restrict__ BT,
    float* __restrict__ Cf, u16* __restrict__ Qb, u16* __restrict__ Kp,
    u16* __restrict__ Vp, int K, int ldc) {
  __shared__ u16 As[128 * 32];
  __shared__ u16 Bs[128 * 32];
  const int tid = threadIdx.x;
  const int wave = tid >> 6, lane = tid & 63;
  const int row0 = blockIdx.y * 128, col0 = blockIdx.x * 128;
  const int wr = (wave >> 1) * 64, wc = (wave & 1) * 64;
  const int r = lane & 15, q8 = (lane >> 4) * 8;

  f32x4 acc[4][4] = {};

  const int sRow = lane >> 2, sK = (lane & 3) * 8;
  const u16* Ag0 = A + (size_t)(row0 + wave * 32 + sRow) * K + sK;
  const u16* Ag1 = Ag0 + (size_t)16 * K;
  const u16* Bg0 = BT + (size_t)(col0 + wave * 32 + sRow) * K + sK;
  const u16* Bg1 = Bg0 + (size_t)16 * K;
  u16* Al0 = &As[wave * 1024];
  u16* Al1 = Al0 + 512;
  u16* Bl0 = &Bs[wave * 1024];
  u16* Bl1 = Bl0 + 512;

  for (int k0 = 0; k0 < K; k0 += 32) {
    async16(Ag0 + k0, Al0);
    async16(Ag1 + k0, Al1);
    async16(Bg0 + k0, Bl0);
    async16(Bg1 + k0, Bl1);
    __syncthreads();
    s16x8 af[4], bf[4];
    #pragma unroll
    for (int t = 0; t < 4; t++) {
      af[t] = *reinterpret_cast<const s16x8*>(&As[(wr + t * 16 + r) * 32 + q8]);
      bf[t] = *reinterpret_cast<const s16x8*>(&Bs[(wc + t * 16 + r) * 32 + q8]);
    }
    #pragma unroll
    for (int i = 0; i < 4; i++)
      #pragma unroll
      for (int j = 0; j < 4; j++)
        acc[i][j] = __builtin_amdgcn_mfma_f32_16x16x32_bf16(af[i], bf[j], acc[i][j], 0, 0, 0);
    __syncthreads();
  }

  const int quad = lane >> 4;
  #pragma unroll
  for (int i = 0; i < 4; i++) {
    const int n = row0 + wr + i * 16 + quad * 4;   // global row for regs 0..3
    const int b = n >> 11, nn = n & (SEQ - 1);
    #pragma unroll
    for (int j = 0; j < 4; j++) {
      const int gc = col0 + wc + j * 16 + r;       // wave-uniform region
      if (MODE == 1) {
        #pragma unroll
        for (int reg = 0; reg < 4; reg++)
          Cf[(size_t)(n + reg) * ldc + gc] = acc[i][j][reg];
      } else if (gc < INTER) {                     // q: row-major, scaled
        size_t base = (size_t)n * INTER + gc;
        #pragma unroll
        for (int reg = 0; reg < 4; reg++)
          Qb[base + (size_t)reg * INTER] = f2bf(acc[i][j][reg] * QSCALE);
      } else if (gc < 2 * INTER) {                 // k -> Kp packed, stride-8 stores
        int dim = gc - INTER, h = dim >> 6, d = dim & 63;
        int bh = b * NHEAD + h;
        size_t base = (((size_t)(bh * 64 + (nn >> 5)) * 4 + (d >> 4)) * 64 +
                       ((((d >> 3) & 1) << 5) | (nn & 31))) * 8 + (d & 7);
        #pragma unroll
        for (int reg = 0; reg < 4; reg++)
          Kp[base + reg * 8] = f2bf(acc[i][j][reg]);
      } else {                                     // v -> Vp packed, b64 store
        int dim = gc - 2 * INTER, h = dim >> 6, d = dim & 63;
        int bh = b * NHEAD + h;
        size_t base = ((((size_t)(bh * 64 + (nn >> 5)) * 2 + ((nn >> 4) & 1)) * 2 +
                        (d >> 5)) * 64 +
                       ((((nn >> 3) & 1) << 5) | (d & 31))) * 8 + (nn & 7);
        uint2 pk;
        pk.x = pk2bf(acc[i][j][0], acc[i][j][1]);
        pk.y = pk2bf(acc[i][j][2], acc[i][j][3]);
        *reinterpret_cast<uint2*>(Vp + base) = pk;
      }
    }
  }
}

// ---------------- flash-style attention, fragment-packed operands ----------------
// grid: (B*H, SEQ/128); block 256 = 4 waves; wave owns 32 q-rows; no barriers.
// R4-measured-best loop body (kn prefetch + copy; NO unroll-2 — R5/R6 showed
// the alternating-buffer unroll regresses ~5 µs).
// S^T = K·Q^T via 32x32x16 MFMA. q pre-scaled by SCALE*log2e -> p = exp2(s).
// No max-shift (scores bounded ~|s|<4 by construction).
// K/V fragments are dense 1 KB loads from packed layouts (lane*16B).
// P round-trips per-wave LDS (stride 36 u16, conflict-free).
__global__ __launch_bounds__(256, 4) void attn_kernel(
    const u16* __restrict__ Qb, const u16* __restrict__ Kp,
    const u16* __restrict__ Vp, u16* __restrict__ AO) {
  __shared__ __align__(16) u16 Ps[4][32 * 36];
  const int tid = threadIdx.x;
  const int wave = tid >> 6, lane = tid & 63;
  const int l31 = lane & 31, half = lane >> 5;
  const int bh = blockIdx.x, b = bh >> 4, h = bh & 15;
  const int i0 = blockIdx.y * 128 + wave * 32;

  // Q fragments (B-operand): B[n=q-row][k=d], k-contiguous. Once per wave.
  const u16* qbase = Qb + (size_t)(b * SEQ + i0 + l31) * INTER + h * HDIM + half * 8;
  s16x8 qf[4];
  #pragma unroll
  for (int c = 0; c < 4; c++) qf[c] = *reinterpret_cast<const s16x8*>(qbase + c * 16);

  const u16* kpb = Kp + (size_t)bh * (64 * 4 * 512) + lane * 8;   // + jblk*2048 + c*512
  const u16* vpb = Vp + (size_t)bh * (64 * 4 * 512) + lane * 8;   // + jblk*2048 + (kc*2+dgrp)*512
  u16* Pw = &Ps[wave][0];

  f32x16 ot0 = {}, ot1 = {};
  float ls = 0.f;

  // prologue: K fragments for jblk = 0
  s16x8 kf[4];
  #pragma unroll
  for (int c = 0; c < 4; c++)
    kf[c] = *reinterpret_cast<const s16x8*>(kpb + c * 512);

  for (int jb = 0; jb < 64; jb++) {
    // prefetch next K tile (wraps on last iter; values unused)
    const int jn = (jb + 1) & 63;
    s16x8 kn[4];
    #pragma unroll
    for (int c = 0; c < 4; c++)
      kn[c] = *reinterpret_cast<const s16x8*>(kpb + jn * 2048 + c * 512);
    // V fragments for THIS tile — issued early, consumed after exp/LDS stage
    s16x8 vf[4];
    #pragma unroll
    for (int c = 0; c < 4; c++)   // c = kc*2 + dgrp
      vf[c] = *reinterpret_cast<const s16x8*>(vpb + jb * 2048 + c * 512);

    // S^T[j][i] = sum_d K[j][d] Q[i][d]  (A = K rows, B = Q rows)
    f32x16 st = {};
    #pragma unroll
    for (int c = 0; c < 4; c++)
      st = __builtin_amdgcn_mfma_f32_32x32x16_bf16(kf[c], qf[c], st, 0, 0, 0);

    // p = exp2(s); per-lane partial row-sum; packed b64 writes into P[i][j]
    #pragma unroll
    for (int q = 0; q < 4; q++) {
      float p0 = EXP2F(st[q * 4 + 0]), p1 = EXP2F(st[q * 4 + 1]);
      float p2 = EXP2F(st[q * 4 + 2]), p3 = EXP2F(st[q * 4 + 3]);
      ls += (p0 + p1) + (p2 + p3);
      uint2 pk;
      pk.x = pk2bf(p0, p1);
      pk.y = pk2bf(p2, p3);
      *reinterpret_cast<uint2*>(&Pw[l31 * 36 + q * 8 + half * 4]) = pk;
    }

    __threadfence_block();  // order Ps writes before A-layout re-read (within wave)

    // O^T[d][i] += sum_j V^T[d][j] P[i][j]  (A = V^T rows, B = P)
    #pragma unroll
    for (int kc = 0; kc < 2; kc++) {
      const u16* pp = &Pw[l31 * 36 + half * 8 + kc * 16];
      s16x4 plo = *reinterpret_cast<const s16x4*>(pp);
      s16x4 phi = *reinterpret_cast<const s16x4*>(pp + 4);
      s16x8 pb = __builtin_shufflevector(plo, phi, 0, 1, 2, 3, 4, 5, 6, 7);
      ot0 = __builtin_amdgcn_mfma_f32_32x32x16_bf16(vf[kc * 2 + 0], pb, ot0, 0, 0, 0);
      ot1 = __builtin_amdgcn_mfma_f32_32x32x16_bf16(vf[kc * 2 + 1], pb, ot1, 0, 0, 0);
    }

    #pragma unroll
    for (int c = 0; c < 4; c++) kf[c] = kn[c];
  }

  ls += __shfl_xor(ls, 32, 64);      // lanes L, L+32 hold complementary j-halves
  float rinv = 1.0f / ls;

  u16* orow = AO + (size_t)(b * SEQ + i0 + l31) * INTER + h * HDIM;
  #pragma unroll
  for (int dt = 0; dt < 2; dt++) {
    const f32x16& o = dt ? ot1 : ot0;
    #pragma unroll
    for (int q = 0; q < 4; q++) {
      uint2 pk;
      pk.x = pk2bf(o[q * 4 + 0] * rinv, o[q * 4 + 1] * rinv);
      pk.y = pk2bf(o[q * 4 + 2] * rinv, o[q * 4 + 3] * rinv);
      *reinterpret_cast<uint2*>(orow + dt * 32 + q * 8 + half * 4) = pk;
    }
  }
}

extern "C" void kernel_launch(void* const* d_in, const int* in_sizes, int n_in,
                              void* d_out, int out_size, void* d_ws, size_t ws_size,
                              hipStream_t stream) {
  const float* features = (const float*)d_in[0];
  const float* W_qkv    = (const float*)d_in[1];
  const float* W_out    = (const float*)d_in[2];
  float* out = (float*)d_out;
  char* w = (char*)d_ws;
  u16* Xb    = (u16*)(w);              // [8192][1024] bf16 features      16 MB
  u16* WqkvT = (u16*)(w + 16777216);   // [3072][1024] bf16 W_qkv^T        6 MB
  u16* WoutT = (u16*)(w + 23068672);   // [1024][1024] bf16 W_out^T        2 MB
  u16* Qb    = (u16*)(w + 25165824);   // [8192][1024] bf16 q (scaled)    16 MB
  u16* Kp    = (u16*)(w + 41943040);   // fragment-packed K               16 MB
  u16* Vp    = (u16*)(w + 58720256);   // fragment-packed V               16 MB
  u16* AO    = (u16*)(w + 75497472);   // [8192][1024] bf16 attn out      16 MB

  prep<<<dim3(12288), dim3(256), 0, stream>>>(features, W_qkv, W_out, Xb, WqkvT, WoutT);
  gemm_bt<0><<<dim3(24, 64), dim3(256), 0, stream>>>(Xb, WqkvT, nullptr, Qb, Kp, Vp,
                                                     DMODEL, 0);
  attn_kernel<<<dim3(64, 16), dim3(256), 0, stream>>>(Qb, Kp, Vp, AO);
  gemm_bt<1><<<dim3(8, 64), dim3(256), 0, stream>>>(AO, WoutT, out, nullptr, nullptr,
                                                    nullptr, INTER, DMODEL);
}